// Round 3
// 333.108 us; speedup vs baseline: 1.0455x; 1.0455x over previous
//
#include <hip/hip_runtime.h>
#include <math.h>
#include <stdint.h>

// Problem constants: B=8, N=2048, D=512, H=16, dk=32
// q = x@Wq^T; k = x@Wk^T; v = x@Wv^T            [t=16384, c=512]
// dw[b,i,j] = exp(-alpha*11*dis[b,i,j])
// w1[b,j,c] = sum_i dw[b,i,j]*exp(k)[b,i,c]*v[b,i,c]
// w2[b,j,c] = sum_i dw[b,i,j]*exp(k)[b,i,c]
// out[b,j,c] = sigmoid(q)[b,j,c] * w1/w2

typedef __bf16 bf16_t;
typedef __attribute__((ext_vector_type(4))) __bf16 bf16x4;
typedef __attribute__((ext_vector_type(8))) __bf16 bf16x8;
typedef __attribute__((ext_vector_type(4))) float f32x4;

#define MFMA_BF16(a, b, c) __builtin_amdgcn_mfma_f32_16x16x32_bf16((a), (b), (c), 0, 0, 0)

static __device__ __forceinline__ void async_ld16(const bf16_t* g, bf16_t* lds) {
  __builtin_amdgcn_global_load_lds(
      reinterpret_cast<__attribute__((address_space(1))) unsigned int*>(
          reinterpret_cast<uintptr_t>(g)),
      reinterpret_cast<__attribute__((address_space(3))) unsigned int*>(
          reinterpret_cast<uintptr_t>(lds)),
      16, 0, 0);
}

// ---- helpers for proj_dw (unchanged, proven): 2-bit XOR swizzle ----
template <int BK, int ROWS>
static __device__ __forceinline__ void stage(const bf16_t* g, int ldg, bf16_t* lds,
                                             int wv, int lane) {
  constexpr int CH = BK / 8;       // 16B chunks per row
  constexpr int RPW = 64 / CH;     // rows per wave-step
  const int r_in = lane / CH;
  const int cpos = lane % CH;
#pragma unroll
  for (int s = 0; s < ROWS / (RPW * 4); ++s) {
    int rbase = wv * (ROWS / 4) + s * RPW;
    int row = rbase + r_in;
    int cg = cpos ^ ((row >> 1) & 3);
    async_ld16(g + (size_t)row * ldg + cg * 8, lds + rbase * BK + lane * 8);
  }
}

template <int BK>
static __device__ __forceinline__ bf16x8 frag_read(const bf16_t* lds, int row16,
                                                   int l15, int quad, int kc) {
  int p = (quad ^ ((l15 >> 1) & 3)) + kc * 4;
  return *(const bf16x8*)&lds[(row16 + l15) * BK + p * 8];
}

// ---- helper for main_gemm: full 3-bit XOR swizzle (conflict-free b128) ----
// stored[row][pos] = global chunk (pos ^ (row&7)); read logical chunk lc at
// pos = lc ^ (row&7). Frag read spans all 8 chunk cols -> all 32 banks.
static __device__ __forceinline__ bf16x8 frag3(const bf16_t* lds, int row16,
                                               int l15, int quad, int kc) {
  int p = (quad | (kc << 2)) ^ (l15 & 7);
  return *(const bf16x8*)&lds[(row16 + l15) * 64 + p * 8];
}

// ---------------- fused fp32 -> bf16 conversion ----------------
// x: 2097152 f32x4; Wq/Wk/Wv: 65536 f32x4 each; total 2293760.
__global__ __launch_bounds__(256) void cvt_all(const float* __restrict__ x,
                                               const float* __restrict__ wq,
                                               const float* __restrict__ wk,
                                               const float* __restrict__ wv,
                                               bf16_t* __restrict__ xb,
                                               bf16_t* __restrict__ wall) {
  int i = blockIdx.x * 256 + threadIdx.x;  // f32x4 index
  if (i >= 2293760) return;
  const float* src;
  bf16_t* dst;
  int off;
  if (i < 2097152) {
    src = x; dst = xb; off = i;
  } else {
    int j = i - 2097152;
    int sel = j >> 16;        // 65536 f32x4 per weight
    off = j & 65535;
    src = (sel == 0) ? wq : (sel == 1) ? wk : wv;
    dst = wall + (size_t)sel * 262144;
  }
  f32x4 f = ((const f32x4*)src)[off];
  bf16x4 o;
  o[0] = (bf16_t)f[0]; o[1] = (bf16_t)f[1]; o[2] = (bf16_t)f[2]; o[3] = (bf16_t)f[3];
  ((bf16x4*)dst)[off] = o;
}

// ---------------- merged projection GEMM + dis-weight transpose ----------------
// (unchanged from proven round: interleaves proj MFMA work with dw HBM streaming)
__global__ __launch_bounds__(256, 4) void proj_dw(const bf16_t* __restrict__ A,
                                                  const bf16_t* __restrict__ W,
                                                  bf16_t* __restrict__ qs,
                                                  bf16_t* __restrict__ kwT,
                                                  bf16_t* __restrict__ kwvT,
                                                  const float* __restrict__ dis,
                                                  bf16_t* __restrict__ dwT,
                                                  const float* __restrict__ alpha) {
  __shared__ __align__(16) char pool[32768];
  const int tid = threadIdx.x;
  const int idx = blockIdx.x;
  const int g19 = idx / 19, r19 = idx % 19;

  if (r19 >= 3) {
    // ---------------- dw path ----------------
    int sub = g19 * 16 + (r19 - 3);
    int jt = sub & 31, it = (sub >> 5) & 31, b = sub >> 10;
    bf16_t* t = (bf16_t*)pool;  // 64*65*2 = 8320 B
    const float coef = -alpha[0] * 11.0f;  // log2(2048) == 11
    const int j0 = jt * 64, i0 = it * 64;
    const int rr = tid >> 4, cc = (tid & 15) * 4;
#pragma unroll
    for (int p = 0; p < 4; ++p) {
      int i = rr + p * 16;
      f32x4 d = *(const f32x4*)&dis[((size_t)(b * 2048 + i0 + i)) * 2048 + j0 + cc];
#pragma unroll
      for (int e = 0; e < 4; ++e) t[(cc + e) * 65 + i] = (bf16_t)__expf(coef * d[e]);
    }
    __syncthreads();
#pragma unroll
    for (int p = 0; p < 4; ++p) {
      int j = rr + p * 16;
      bf16x4 o;
#pragma unroll
      for (int e = 0; e < 4; ++e) o[e] = t[j * 65 + cc + e];
      *(bf16x4*)&dwT[((size_t)(b * 2048 + j0 + j)) * 2048 + i0 + cc] = o;
    }
    return;
  }

  // ---------------- proj path ----------------
  const int sub = g19 * 3 + r19;
  const int m_blk = sub / 12, n_blk = sub % 12;
  bf16_t* As = (bf16_t*)pool;  // 128x64 = 16 KB
  const int K = 512;
  const int wv = tid >> 6, lane = tid & 63;
  const int l15 = lane & 15, quad = lane >> 4;
  const int wm = wv >> 1, wn = wv & 1;
  const bf16_t* Am = A + (size_t)(m_blk * 128) * K;
  const int b = m_blk >> 4;

  if (n_blk < 4) {
    // ---- q path: 128x128 tile, 64x64 wave tiles, BK=64 ----
    bf16_t* Bsq = (bf16_t*)(pool + 16384);  // 128x64 = 16 KB
    const int c_loc = n_blk * 128;
    f32x4 acc[4][4];
#pragma unroll
    for (int a = 0; a < 4; ++a)
#pragma unroll
      for (int c = 0; c < 4; ++c) acc[a][c] = (f32x4){0.f, 0.f, 0.f, 0.f};

    for (int k0 = 0; k0 < K; k0 += 64) {
      stage<64, 128>(Am + k0, K, As, wv, lane);
      stage<64, 128>(W + (size_t)c_loc * K + k0, K, Bsq, wv, lane);
      __syncthreads();
#pragma unroll
      for (int kc = 0; kc < 2; ++kc) {
        bf16x8 a[4], bb[4];
#pragma unroll
        for (int mf = 0; mf < 4; ++mf) a[mf] = frag_read<64>(As, wm * 64 + mf * 16, l15, quad, kc);
#pragma unroll
        for (int nf = 0; nf < 4; ++nf) bb[nf] = frag_read<64>(Bsq, wn * 64 + nf * 16, l15, quad, kc);
#pragma unroll
        for (int mf = 0; mf < 4; ++mf)
#pragma unroll
          for (int nf = 0; nf < 4; ++nf) acc[mf][nf] = MFMA_BF16(a[mf], bb[nf], acc[mf][nf]);
      }
      __syncthreads();
    }
#pragma unroll
    for (int mf = 0; mf < 4; ++mf)
#pragma unroll
      for (int nf = 0; nf < 4; ++nf) {
        int j16 = (m_blk & 15) * 8 + wm * 4 + mf;
        int c16 = n_blk * 8 + wn * 4 + nf;
        bf16x4 o;
#pragma unroll
        for (int r = 0; r < 4; ++r)
          o[r] = (bf16_t)(1.0f / (1.0f + __expf(-acc[mf][nf][r])));
        size_t off = (((size_t)b * 128 + j16) * 32 + c16) * 256 + quad * 64 + l15 * 4;
        *(bf16x4*)&qs[off] = o;
      }
  } else {
    // ---- kv path: 128x64 tile, 64x32 wave tiles, k and v share A staging, BK=64 ----
    bf16_t* Bk = (bf16_t*)(pool + 16384);  // 64x64 = 8 KB
    bf16_t* Bv = (bf16_t*)(pool + 24576);  // 64x64 = 8 KB
    const int c_loc = (n_blk - 4) * 64;
    f32x4 acck[4][2], accv[4][2];
#pragma unroll
    for (int a = 0; a < 4; ++a)
#pragma unroll
      for (int c = 0; c < 2; ++c) {
        acck[a][c] = (f32x4){0.f, 0.f, 0.f, 0.f};
        accv[a][c] = (f32x4){0.f, 0.f, 0.f, 0.f};
      }
    const bf16_t* Wk = W + (size_t)(512 + c_loc) * K;
    const bf16_t* Wv = W + (size_t)(1024 + c_loc) * K;

    for (int k0 = 0; k0 < K; k0 += 64) {
      stage<64, 128>(Am + k0, K, As, wv, lane);
      stage<64, 64>(Wk + k0, K, Bk, wv, lane);
      stage<64, 64>(Wv + k0, K, Bv, wv, lane);
      __syncthreads();
#pragma unroll
      for (int kc = 0; kc < 2; ++kc) {
        bf16x8 a[4], bk[2], bv[2];
#pragma unroll
        for (int mf = 0; mf < 4; ++mf) a[mf] = frag_read<64>(As, wm * 64 + mf * 16, l15, quad, kc);
#pragma unroll
        for (int nf = 0; nf < 2; ++nf) {
          bk[nf] = frag_read<64>(Bk, wn * 32 + nf * 16, l15, quad, kc);
          bv[nf] = frag_read<64>(Bv, wn * 32 + nf * 16, l15, quad, kc);
        }
#pragma unroll
        for (int mf = 0; mf < 4; ++mf)
#pragma unroll
          for (int nf = 0; nf < 2; ++nf) {
            acck[mf][nf] = MFMA_BF16(a[mf], bk[nf], acck[mf][nf]);
            accv[mf][nf] = MFMA_BF16(a[mf], bv[nf], accv[mf][nf]);
          }
      }
      __syncthreads();
    }

    // epilogue: exp/mul + 32-c-chunk transpose through aliased LDS
    bf16_t* Lk = (bf16_t*)pool;            // 32 x 136 = 8704 B
    bf16_t* Lv = (bf16_t*)(pool + 8704);   // 32 x 136 = 8704 B
    const int t0 = (m_blk * 128) & 2047;
#pragma unroll
    for (int ci = 0; ci < 2; ++ci) {
      if (wn == ci) {
#pragma unroll
        for (int mf = 0; mf < 4; ++mf)
#pragma unroll
          for (int nf = 0; nf < 2; ++nf) {
            int cl = nf * 16 + l15;
            int tl = wm * 64 + mf * 16 + quad * 4;
#pragma unroll
            for (int r = 0; r < 4; ++r) {
              float kw = __expf(acck[mf][nf][r]);
              Lk[cl * 136 + tl + r] = (bf16_t)kw;
              Lv[cl * 136 + tl + r] = (bf16_t)(kw * accv[mf][nf][r]);
            }
          }
      }
      __syncthreads();
      {
        int rowt = tid >> 3, colt = (tid & 7) * 16;
        int c = c_loc + ci * 32 + rowt;
        size_t g = ((size_t)b * 512 + c) * 2048 + t0 + colt;
        *(bf16x8*)&kwT[g] = *(const bf16x8*)&Lk[rowt * 136 + colt];
        *(bf16x8*)&kwT[g + 8] = *(const bf16x8*)&Lk[rowt * 136 + colt + 8];
        *(bf16x8*)&kwvT[g] = *(const bf16x8*)&Lv[rowt * 136 + colt];
        *(bf16x8*)&kwvT[g + 8] = *(const bf16x8*)&Lv[rowt * 136 + colt + 8];
      }
      __syncthreads();
    }
  }
}

// ---------------- main batched GEMM + fused epilogue (256^2 / 8-wave / phase-split) ----------------
// Grid = 256 blocks (1 per CU): i -> b = i&7 (XCD), nbb = (i>>3)&3, mb = i>>5.
// Block tile 256(j) x 256(interleaved n). 8 waves = 2(m) x 4(n); wave owns 128x64.
// B rows interleaved by 16: type=(n>>4)&1 (0=kwv->w1, 1=kw->w2), c = nbb*128+(n>>5)*16+(n&15).
// K-loop: BK=64, 32 tiles, double-buffered 128 KB LDS. Per tile 4 phases x 16 MFMA
// (C-quadrants), raw s_barrier fencing + setprio around MFMA clusters; all 8
// prefetch loads for tile t+1 burst-issued at phase 0 of tile t -> ~3.5 phases of
// MFMA cover before the single tile-boundary drain (__syncthreads).
__global__ __launch_bounds__(512, 2) void main_gemm(const bf16_t* __restrict__ dwT,
                                                    const bf16_t* __restrict__ kwvT,
                                                    const bf16_t* __restrict__ kwT,
                                                    const bf16_t* __restrict__ qs,
                                                    float* __restrict__ out) {
  extern __shared__ __align__(16) char smem_raw[];
  bf16_t* const lds = (bf16_t*)smem_raw;  // [2 buf][A 16384 | B 16384] elements
  const int K = 2048;
  const int tid = threadIdx.x;
  const int wv = tid >> 6, lane = tid & 63;
  const int l15 = lane & 15, quad = lane >> 4;
  const int bi = blockIdx.x;
  const int b = bi & 7, nbb = (bi >> 3) & 3, mb = bi >> 5;
  const int wm = wv >> 2, wn = wv & 3;       // 2 m-waves x 4 n-waves
  const int r_in = lane >> 3, cpos = lane & 7;
  const int cg = cpos ^ r_in;                // 3-bit swizzled source chunk (row&7 == r_in)

  const bf16_t* const Ab = dwT + ((size_t)b * 2048 + mb * 256) * K;
  const bf16_t* const BvB = kwvT + (size_t)b * 512 * K;
  const bf16_t* const BkB = kwT + (size_t)b * 512 * K;

  // per-thread source pointers for the 4 A-loads and 4 B-loads of one K-tile
  const bf16_t* aSrc[4];
  const bf16_t* bSrc[4];
#pragma unroll
  for (int s = 0; s < 4; ++s) {
    const int row = s * 64 + wv * 8 + r_in;  // LDS row 0..255
    aSrc[s] = Ab + (size_t)row * K + cg * 8;
    const int type = (row >> 4) & 1;         // 8-row band never crosses 16
    const int crow = nbb * 128 + (row >> 5) * 16 + (row & 15);
    const bf16_t* base = type ? BkB : BvB;
    bSrc[s] = base + (size_t)crow * K + cg * 8;
  }

  f32x4 acc[8][4];
#pragma unroll
  for (int m = 0; m < 8; ++m)
#pragma unroll
    for (int n = 0; n < 4; ++n) acc[m][n] = (f32x4){0.f, 0.f, 0.f, 0.f};

  bf16x8 a[8];   // current A m-half: [mf*2+kc]
  bf16x8 b0[4];  // B n-half 0: [nf*2+kc]
  bf16x8 b1[4];  // B n-half 1

#define STAGE_T(dst, koff)                                                         \
  do {                                                                             \
    bf16_t* A_ = lds + (dst)*32768;                                                \
    _Pragma("unroll") for (int s = 0; s < 4; ++s)                                  \
        async_ld16(aSrc[s] + (koff), A_ + s * 4096 + wv * 512 + lane * 8);         \
    _Pragma("unroll") for (int s = 0; s < 4; ++s)                                  \
        async_ld16(bSrc[s] + (koff), A_ + 16384 + s * 4096 + wv * 512 + lane * 8); \
  } while (0)

#define LOADA(As_, mh)                                                             \
  do {                                                                             \
    _Pragma("unroll") for (int mf = 0; mf < 4; ++mf)                               \
        _Pragma("unroll") for (int kc = 0; kc < 2; ++kc)                           \
            a[mf * 2 + kc] =                                                       \
        frag3((As_), wm * 128 + (mh)*64 + mf * 16, l15, quad, kc);                 \
  } while (0)

#define LOADB(Bs_, dstarr, nh)                                                     \
  do {                                                                             \
    _Pragma("unroll") for (int nf = 0; nf < 2; ++nf)                               \
        _Pragma("unroll") for (int kc = 0; kc < 2; ++kc)                           \
            dstarr[nf * 2 + kc] =                                                  \
        frag3((Bs_), wn * 64 + (nh)*32 + nf * 16, l15, quad, kc);                  \
  } while (0)

#define MFMA_PH(mh, nh, barr)                                                      \
  do {                                                                             \
    __builtin_amdgcn_s_setprio(1);                                                 \
    _Pragma("unroll") for (int kc = 0; kc < 2; ++kc)                               \
        _Pragma("unroll") for (int mf = 0; mf < 4; ++mf)                           \
            _Pragma("unroll") for (int nf = 0; nf < 2; ++nf)                       \
                acc[(mh)*4 + mf][(nh)*2 + nf] =                                    \
        MFMA_BF16(a[mf * 2 + kc], barr[nf * 2 + kc], acc[(mh)*4 + mf][(nh)*2 + nf]); \
    __builtin_amdgcn_s_setprio(0);                                                 \
  } while (0)

  // prologue: stage tile 0 into buf0
  STAGE_T(0, 0);
  __syncthreads();

  for (int t = 0; t < 32; ++t) {
    const int c = t & 1;
    const bf16_t* As_c = lds + c * 32768;
    const bf16_t* Bs_c = As_c + 16384;
    // phase 0: burst-issue prefetch of tile t+1; read A[m0], B[n0]; mfma (m0,n0)
    if (t < 31) STAGE_T(c ^ 1, (t + 1) * 64);
    LOADA(As_c, 0);
    LOADB(Bs_c, b0, 0);
    __builtin_amdgcn_s_barrier();
    MFMA_PH(0, 0, b0);
    __builtin_amdgcn_s_barrier();
    // phase 1: read B[n1]; mfma (m0,n1)
    LOADB(Bs_c, b1, 1);
    __builtin_amdgcn_s_barrier();
    MFMA_PH(0, 1, b1);
    __builtin_amdgcn_s_barrier();
    // phase 2: read A[m1]; mfma (m1,n1)
    LOADA(As_c, 1);
    __builtin_amdgcn_s_barrier();
    MFMA_PH(1, 1, b1);
    __builtin_amdgcn_s_barrier();
    // phase 3: mfma (m1,n0); tile transition (drains prefetch, ~600cy of cover)
    MFMA_PH(1, 0, b0);
    __syncthreads();
  }

#undef STAGE_T
#undef LOADA
#undef LOADB
#undef MFMA_PH

  // epilogue: nf even = w1 (kwv), nf odd = w2 (kw); pair in registers.
#pragma unroll
  for (int mf = 0; mf < 8; ++mf)
#pragma unroll
    for (int p = 0; p < 2; ++p) {
      f32x4 w1 = acc[mf][2 * p];
      f32x4 w2 = acc[mf][2 * p + 1];
      const int j16 = mb * 16 + wm * 8 + mf;
      const int c16 = nbb * 8 + wn * 2 + p;
      size_t qoff = (((size_t)b * 128 + j16) * 32 + c16) * 256 + quad * 64 + l15 * 4;
      bf16x4 qv = *(const bf16x4*)&qs[qoff];
      const int ccol = c16 * 16 + l15;
#pragma unroll
      for (int r = 0; r < 4; ++r) {
        const int j = j16 * 16 + quad * 4 + r;
        out[((size_t)b * 2048 + j) * 512 + ccol] = (float)qv[r] * (w1[r] / w2[r]);
      }
    }
}

extern "C" void kernel_launch(void* const* d_in, const int* in_sizes, int n_in,
                              void* d_out, int out_size, void* d_ws, size_t ws_size,
                              hipStream_t stream) {
  const float* x = (const float*)d_in[0];
  const float* dis = (const float*)d_in[1];
  const float* Wq = (const float*)d_in[2];
  const float* Wk = (const float*)d_in[3];
  const float* Wv = (const float*)d_in[4];
  const float* alpha = (const float*)d_in[5];
  float* out = (float*)d_out;

  char* p = (char*)d_ws;
  bf16_t* x_bf = (bf16_t*)p;  p += (size_t)16384 * 512 * 2;       // 16 MB
  bf16_t* Wall = (bf16_t*)p;  p += (size_t)1536 * 512 * 2;        // 1.5 MB
  bf16_t* kwT  = (bf16_t*)p;  p += (size_t)8 * 512 * 2048 * 2;    // 16 MB
  bf16_t* kwvT = (bf16_t*)p;  p += (size_t)8 * 512 * 2048 * 2;    // 16 MB
  bf16_t* dwT  = (bf16_t*)p;  p += (size_t)8 * 2048 * 2048 * 2;   // 64 MB
  bf16_t* qs_bf = (bf16_t*)p; p += (size_t)16384 * 512 * 2;       // 16 MB (blocked layout)
  if ((size_t)(p - (char*)d_ws) > ws_size) return;  // ws too small: fail visibly

  // 128 KB dynamic LDS for main_gemm (>64 KB needs the opt-in attribute;
  // hipFuncSetAttribute is not a stream op -> graph-capture safe).
  static bool attr_done = false;
  if (!attr_done) {
    hipFuncSetAttribute(reinterpret_cast<const void*>(main_gemm),
                        hipFuncAttributeMaxDynamicSharedMemorySize, 131072);
    attr_done = true;
  }

  cvt_all<<<8960, 256, 0, stream>>>(x, Wq, Wk, Wv, x_bf, Wall);
  proj_dw<<<9728, 256, 0, stream>>>(x_bf, Wall, qs_bf, kwT, kwvT, dis, dwT, alpha);
  main_gemm<<<256, 512, 131072, stream>>>(dwT, kwvT, kwT, qs_bf, out);
}

// Round 6
// 313.674 us; speedup vs baseline: 1.1103x; 1.0620x over previous
//
#include <hip/hip_runtime.h>
#include <math.h>
#include <stdint.h>

// Problem constants: B=8, N=2048, D=512, H=16, dk=32
// q = x@Wq^T; k = x@Wk^T; v = x@Wv^T            [t=16384, c=512]
// dw[b,i,j] = exp(-alpha*11*dis[b,i,j])
// w1[b,j,c] = sum_i dw[b,i,j]*exp(k)[b,i,c]*v[b,i,c]
// w2[b,j,c] = sum_i dw[b,i,j]*exp(k)[b,i,c]
// out[b,j,c] = sigmoid(q)[b,j,c] * w1/w2

typedef __bf16 bf16_t;
typedef __attribute__((ext_vector_type(4))) __bf16 bf16x4;
typedef __attribute__((ext_vector_type(8))) __bf16 bf16x8;
typedef __attribute__((ext_vector_type(4))) float f32x4;

#define MFMA_BF16(a, b, c) __builtin_amdgcn_mfma_f32_16x16x32_bf16((a), (b), (c), 0, 0, 0)

static __device__ __forceinline__ void async_ld16(const bf16_t* g, bf16_t* lds) {
  __builtin_amdgcn_global_load_lds(
      reinterpret_cast<__attribute__((address_space(1))) unsigned int*>(
          reinterpret_cast<uintptr_t>(g)),
      reinterpret_cast<__attribute__((address_space(3))) unsigned int*>(
          reinterpret_cast<uintptr_t>(lds)),
      16, 0, 0);
}

// ---- 3-bit XOR swizzle pair (hardware-validated in round-3 main_gemm) ----
// Stage ROWS x 64 bf16 tile: stored[row][pos] holds global chunk (pos ^ (row&7));
// swizzle applied via per-lane SOURCE address, LDS dest stays linear (rule #21).
// rbase is always a multiple of 8 -> row&7 == lane>>3 for every staged row.
template <int ROWS>
static __device__ __forceinline__ void stage3(const bf16_t* g, int ldg, bf16_t* lds,
                                              int wv, int lane) {
  const int r_in = lane >> 3;      // 8 chunks per 64-wide row
  const int cpos = lane & 7;
#pragma unroll
  for (int s = 0; s < ROWS / 32; ++s) {
    int rbase = wv * (ROWS / 4) + s * 8;   // multiple of 8 -> row&7 == r_in
    int row = rbase + r_in;
    int cg = cpos ^ (row & 7);
    async_ld16(g + (size_t)row * ldg + cg * 8, lds + rbase * 64 + lane * 8);
  }
}

// Swizzled fragment read (BK=64): logical chunk lc read at pos = lc ^ (row&7).
// Spans all 8 chunk cols -> all 32 banks, conflict-free b128.
static __device__ __forceinline__ bf16x8 frag3(const bf16_t* lds, int row16,
                                               int l15, int quad, int kc) {
  int p = (quad | (kc << 2)) ^ (l15 & 7);
  return *(const bf16x8*)&lds[(row16 + l15) * 64 + p * 8];
}

// ---------------- fused fp32 -> bf16 conversion ----------------
// x: 2097152 f32x4; Wq/Wk/Wv: 65536 f32x4 each; total 2293760.
__global__ __launch_bounds__(256) void cvt_all(const float* __restrict__ x,
                                               const float* __restrict__ wq,
                                               const float* __restrict__ wk,
                                               const float* __restrict__ wv,
                                               bf16_t* __restrict__ xb,
                                               bf16_t* __restrict__ wall) {
  int i = blockIdx.x * 256 + threadIdx.x;  // f32x4 index
  if (i >= 2293760) return;
  const float* src;
  bf16_t* dst;
  int off;
  if (i < 2097152) {
    src = x; dst = xb; off = i;
  } else {
    int j = i - 2097152;
    int sel = j >> 16;        // 65536 f32x4 per weight
    off = j & 65535;
    src = (sel == 0) ? wq : (sel == 1) ? wk : wv;
    dst = wall + (size_t)sel * 262144;
  }
  f32x4 f = ((const f32x4*)src)[off];
  bf16x4 o;
  o[0] = (bf16_t)f[0]; o[1] = (bf16_t)f[1]; o[2] = (bf16_t)f[2]; o[3] = (bf16_t)f[3];
  ((bf16x4*)dst)[off] = o;
}

// ---------------- merged projection GEMM + dis-weight transpose ----------------
// proj paths upgraded to the 3-bit swizzle pair (kills the 3.5M bank-conflict
// cycles measured in round 3); dw path and epilogues untouched (proven).
__global__ __launch_bounds__(256, 4) void proj_dw(const bf16_t* __restrict__ A,
                                                  const bf16_t* __restrict__ W,
                                                  bf16_t* __restrict__ qs,
                                                  bf16_t* __restrict__ kwT,
                                                  bf16_t* __restrict__ kwvT,
                                                  const float* __restrict__ dis,
                                                  bf16_t* __restrict__ dwT,
                                                  const float* __restrict__ alpha) {
  __shared__ __align__(16) char pool[32768];
  const int tid = threadIdx.x;
  const int idx = blockIdx.x;
  const int g19 = idx / 19, r19 = idx % 19;

  if (r19 >= 3) {
    // ---------------- dw path ----------------
    int sub = g19 * 16 + (r19 - 3);
    int jt = sub & 31, it = (sub >> 5) & 31, b = sub >> 10;
    bf16_t* t = (bf16_t*)pool;  // 64*65*2 = 8320 B
    const float coef = -alpha[0] * 11.0f;  // log2(2048) == 11
    const int j0 = jt * 64, i0 = it * 64;
    const int rr = tid >> 4, cc = (tid & 15) * 4;
#pragma unroll
    for (int p = 0; p < 4; ++p) {
      int i = rr + p * 16;
      f32x4 d = *(const f32x4*)&dis[((size_t)(b * 2048 + i0 + i)) * 2048 + j0 + cc];
#pragma unroll
      for (int e = 0; e < 4; ++e) t[(cc + e) * 65 + i] = (bf16_t)__expf(coef * d[e]);
    }
    __syncthreads();
#pragma unroll
    for (int p = 0; p < 4; ++p) {
      int j = rr + p * 16;
      bf16x4 o;
#pragma unroll
      for (int e = 0; e < 4; ++e) o[e] = t[j * 65 + cc + e];
      *(bf16x4*)&dwT[((size_t)(b * 2048 + j0 + j)) * 2048 + i0 + cc] = o;
    }
    return;
  }

  // ---------------- proj path ----------------
  const int sub = g19 * 3 + r19;
  const int m_blk = sub / 12, n_blk = sub % 12;
  bf16_t* As = (bf16_t*)pool;  // 128x64 = 16 KB
  const int K = 512;
  const int wv = tid >> 6, lane = tid & 63;
  const int l15 = lane & 15, quad = lane >> 4;
  const int wm = wv >> 1, wn = wv & 1;
  const bf16_t* Am = A + (size_t)(m_blk * 128) * K;
  const int b = m_blk >> 4;

  if (n_blk < 4) {
    // ---- q path: 128x128 tile, 64x64 wave tiles, BK=64 ----
    bf16_t* Bsq = (bf16_t*)(pool + 16384);  // 128x64 = 16 KB
    const int c_loc = n_blk * 128;
    f32x4 acc[4][4];
#pragma unroll
    for (int a = 0; a < 4; ++a)
#pragma unroll
      for (int c = 0; c < 4; ++c) acc[a][c] = (f32x4){0.f, 0.f, 0.f, 0.f};

    for (int k0 = 0; k0 < K; k0 += 64) {
      stage3<128>(Am + k0, K, As, wv, lane);
      stage3<128>(W + (size_t)c_loc * K + k0, K, Bsq, wv, lane);
      __syncthreads();
#pragma unroll
      for (int kc = 0; kc < 2; ++kc) {
        bf16x8 a[4], bb[4];
#pragma unroll
        for (int mf = 0; mf < 4; ++mf) a[mf] = frag3(As, wm * 64 + mf * 16, l15, quad, kc);
#pragma unroll
        for (int nf = 0; nf < 4; ++nf) bb[nf] = frag3(Bsq, wn * 64 + nf * 16, l15, quad, kc);
#pragma unroll
        for (int mf = 0; mf < 4; ++mf)
#pragma unroll
          for (int nf = 0; nf < 4; ++nf) acc[mf][nf] = MFMA_BF16(a[mf], bb[nf], acc[mf][nf]);
      }
      __syncthreads();
    }
#pragma unroll
    for (int mf = 0; mf < 4; ++mf)
#pragma unroll
      for (int nf = 0; nf < 4; ++nf) {
        int j16 = (m_blk & 15) * 8 + wm * 4 + mf;
        int c16 = n_blk * 8 + wn * 4 + nf;
        bf16x4 o;
#pragma unroll
        for (int r = 0; r < 4; ++r)
          o[r] = (bf16_t)(1.0f / (1.0f + __expf(-acc[mf][nf][r])));
        size_t off = (((size_t)b * 128 + j16) * 32 + c16) * 256 + quad * 64 + l15 * 4;
        *(bf16x4*)&qs[off] = o;
      }
  } else {
    // ---- kv path: 128x64 tile, 64x32 wave tiles, k and v share A staging, BK=64 ----
    bf16_t* Bk = (bf16_t*)(pool + 16384);  // 64x64 = 8 KB
    bf16_t* Bv = (bf16_t*)(pool + 24576);  // 64x64 = 8 KB
    const int c_loc = (n_blk - 4) * 64;
    f32x4 acck[4][2], accv[4][2];
#pragma unroll
    for (int a = 0; a < 4; ++a)
#pragma unroll
      for (int c = 0; c < 2; ++c) {
        acck[a][c] = (f32x4){0.f, 0.f, 0.f, 0.f};
        accv[a][c] = (f32x4){0.f, 0.f, 0.f, 0.f};
      }
    const bf16_t* Wk = W + (size_t)(512 + c_loc) * K;
    const bf16_t* Wv = W + (size_t)(1024 + c_loc) * K;

    for (int k0 = 0; k0 < K; k0 += 64) {
      stage3<128>(Am + k0, K, As, wv, lane);
      stage3<64>(Wk + k0, K, Bk, wv, lane);
      stage3<64>(Wv + k0, K, Bv, wv, lane);
      __syncthreads();
#pragma unroll
      for (int kc = 0; kc < 2; ++kc) {
        bf16x8 a[4], bk[2], bv[2];
#pragma unroll
        for (int mf = 0; mf < 4; ++mf) a[mf] = frag3(As, wm * 64 + mf * 16, l15, quad, kc);
#pragma unroll
        for (int nf = 0; nf < 2; ++nf) {
          bk[nf] = frag3(Bk, wn * 32 + nf * 16, l15, quad, kc);
          bv[nf] = frag3(Bv, wn * 32 + nf * 16, l15, quad, kc);
        }
#pragma unroll
        for (int mf = 0; mf < 4; ++mf)
#pragma unroll
          for (int nf = 0; nf < 2; ++nf) {
            acck[mf][nf] = MFMA_BF16(a[mf], bk[nf], acck[mf][nf]);
            accv[mf][nf] = MFMA_BF16(a[mf], bv[nf], accv[mf][nf]);
          }
      }
      __syncthreads();
    }

    // epilogue: exp/mul + 32-c-chunk transpose through aliased LDS
    bf16_t* Lk = (bf16_t*)pool;            // 32 x 136 = 8704 B
    bf16_t* Lv = (bf16_t*)(pool + 8704);   // 32 x 136 = 8704 B
    const int t0 = (m_blk * 128) & 2047;
#pragma unroll
    for (int ci = 0; ci < 2; ++ci) {
      if (wn == ci) {
#pragma unroll
        for (int mf = 0; mf < 4; ++mf)
#pragma unroll
          for (int nf = 0; nf < 2; ++nf) {
            int cl = nf * 16 + l15;
            int tl = wm * 64 + mf * 16 + quad * 4;
#pragma unroll
            for (int r = 0; r < 4; ++r) {
              float kw = __expf(acck[mf][nf][r]);
              Lk[cl * 136 + tl + r] = (bf16_t)kw;
              Lv[cl * 136 + tl + r] = (bf16_t)(kw * accv[mf][nf][r]);
            }
          }
      }
      __syncthreads();
      {
        int rowt = tid >> 3, colt = (tid & 7) * 16;
        int c = c_loc + ci * 32 + rowt;
        size_t g = ((size_t)b * 512 + c) * 2048 + t0 + colt;
        *(bf16x8*)&kwT[g] = *(const bf16x8*)&Lk[rowt * 136 + colt];
        *(bf16x8*)&kwT[g + 8] = *(const bf16x8*)&Lk[rowt * 136 + colt + 8];
        *(bf16x8*)&kwvT[g] = *(const bf16x8*)&Lv[rowt * 136 + colt];
        *(bf16x8*)&kwvT[g + 8] = *(const bf16x8*)&Lv[rowt * 136 + colt + 8];
      }
      __syncthreads();
    }
  }
}

// ---------------- main batched GEMM + fused epilogue (256^2 / 8-wave / phase-split) ----------------
// REVERTED verbatim to the round-3 hardware-verified version. 2 buffers x 64 KB
// = 128 KB LDS (3-deep at this tile size needs 192 KB > 160 KB HW limit — the
// round-4 failure). Grid = 256 blocks (1/CU): b = bi&7 (XCD), nbb, mb.
// Per tile: 4 phases x 16 MFMA; prefetch burst at phase 0; boundary __syncthreads.
__global__ __launch_bounds__(512, 2) void main_gemm(const bf16_t* __restrict__ dwT,
                                                    const bf16_t* __restrict__ kwvT,
                                                    const bf16_t* __restrict__ kwT,
                                                    const bf16_t* __restrict__ qs,
                                                    float* __restrict__ out) {
  extern __shared__ __align__(16) char smem_raw[];
  bf16_t* const lds = (bf16_t*)smem_raw;  // [2 buf][A 16384 | B 16384] elements
  const int K = 2048;
  const int tid = threadIdx.x;
  const int wv = tid >> 6, lane = tid & 63;
  const int l15 = lane & 15, quad = lane >> 4;
  const int bi = blockIdx.x;
  const int b = bi & 7, nbb = (bi >> 3) & 3, mb = bi >> 5;
  const int wm = wv >> 2, wn = wv & 3;       // 2 m-waves x 4 n-waves
  const int r_in = lane >> 3, cpos = lane & 7;
  const int cg = cpos ^ r_in;                // 3-bit swizzled source chunk (row&7 == r_in)

  const bf16_t* const Ab = dwT + ((size_t)b * 2048 + mb * 256) * K;
  const bf16_t* const BvB = kwvT + (size_t)b * 512 * K;
  const bf16_t* const BkB = kwT + (size_t)b * 512 * K;

  // per-thread source pointers for the 4 A-loads and 4 B-loads of one K-tile
  const bf16_t* aSrc[4];
  const bf16_t* bSrc[4];
#pragma unroll
  for (int s = 0; s < 4; ++s) {
    const int row = s * 64 + wv * 8 + r_in;  // LDS row 0..255
    aSrc[s] = Ab + (size_t)row * K + cg * 8;
    const int type = (row >> 4) & 1;         // 8-row band never crosses 16
    const int crow = nbb * 128 + (row >> 5) * 16 + (row & 15);
    const bf16_t* base = type ? BkB : BvB;
    bSrc[s] = base + (size_t)crow * K + cg * 8;
  }

  f32x4 acc[8][4];
#pragma unroll
  for (int m = 0; m < 8; ++m)
#pragma unroll
    for (int n = 0; n < 4; ++n) acc[m][n] = (f32x4){0.f, 0.f, 0.f, 0.f};

  bf16x8 a[8];   // current A m-half: [mf*2+kc]
  bf16x8 b0[4];  // B n-half 0: [nf*2+kc]
  bf16x8 b1[4];  // B n-half 1

#define STAGE_T(dst, koff)                                                         \
  do {                                                                             \
    bf16_t* A_ = lds + (dst)*32768;                                                \
    _Pragma("unroll") for (int s = 0; s < 4; ++s)                                  \
        async_ld16(aSrc[s] + (koff), A_ + s * 4096 + wv * 512 + lane * 8);         \
    _Pragma("unroll") for (int s = 0; s < 4; ++s)                                  \
        async_ld16(bSrc[s] + (koff), A_ + 16384 + s * 4096 + wv * 512 + lane * 8); \
  } while (0)

#define LOADA(As_, mh)                                                             \
  do {                                                                             \
    _Pragma("unroll") for (int mf = 0; mf < 4; ++mf)                               \
        _Pragma("unroll") for (int kc = 0; kc < 2; ++kc)                           \
            a[mf * 2 + kc] =                                                       \
        frag3((As_), wm * 128 + (mh)*64 + mf * 16, l15, quad, kc);                 \
  } while (0)

#define LOADB(Bs_, dstarr, nh)                                                     \
  do {                                                                             \
    _Pragma("unroll") for (int nf = 0; nf < 2; ++nf)                               \
        _Pragma("unroll") for (int kc = 0; kc < 2; ++kc)                           \
            dstarr[nf * 2 + kc] =                                                  \
        frag3((Bs_), wn * 64 + (nh)*32 + nf * 16, l15, quad, kc);                  \
  } while (0)

#define MFMA_PH(mh, nh, barr)                                                      \
  do {                                                                             \
    __builtin_amdgcn_s_setprio(1);                                                 \
    _Pragma("unroll") for (int kc = 0; kc < 2; ++kc)                               \
        _Pragma("unroll") for (int mf = 0; mf < 4; ++mf)                           \
            _Pragma("unroll") for (int nf = 0; nf < 2; ++nf)                       \
                acc[(mh)*4 + mf][(nh)*2 + nf] =                                    \
        MFMA_BF16(a[mf * 2 + kc], barr[nf * 2 + kc], acc[(mh)*4 + mf][(nh)*2 + nf]); \
    __builtin_amdgcn_s_setprio(0);                                                 \
  } while (0)

  // prologue: stage tile 0 into buf0
  STAGE_T(0, 0);
  __syncthreads();

  for (int t = 0; t < 32; ++t) {
    const int c = t & 1;
    const bf16_t* As_c = lds + c * 32768;
    const bf16_t* Bs_c = As_c + 16384;
    // phase 0: burst-issue prefetch of tile t+1; read A[m0], B[n0]; mfma (m0,n0)
    if (t < 31) STAGE_T(c ^ 1, (t + 1) * 64);
    LOADA(As_c, 0);
    LOADB(Bs_c, b0, 0);
    __builtin_amdgcn_s_barrier();
    MFMA_PH(0, 0, b0);
    __builtin_amdgcn_s_barrier();
    // phase 1: read B[n1]; mfma (m0,n1)
    LOADB(Bs_c, b1, 1);
    __builtin_amdgcn_s_barrier();
    MFMA_PH(0, 1, b1);
    __builtin_amdgcn_s_barrier();
    // phase 2: read A[m1]; mfma (m1,n1)
    LOADA(As_c, 1);
    __builtin_amdgcn_s_barrier();
    MFMA_PH(1, 1, b1);
    __builtin_amdgcn_s_barrier();
    // phase 3: mfma (m1,n0); tile transition (drains prefetch)
    MFMA_PH(1, 0, b0);
    __syncthreads();
  }

#undef STAGE_T
#undef LOADA
#undef LOADB
#undef MFMA_PH

  // epilogue: nf even = w1 (kwv), nf odd = w2 (kw); pair in registers.
#pragma unroll
  for (int mf = 0; mf < 8; ++mf)
#pragma unroll
    for (int p = 0; p < 2; ++p) {
      f32x4 w1 = acc[mf][2 * p];
      f32x4 w2 = acc[mf][2 * p + 1];
      const int j16 = mb * 16 + wm * 8 + mf;
      const int c16 = nbb * 8 + wn * 2 + p;
      size_t qoff = (((size_t)b * 128 + j16) * 32 + c16) * 256 + quad * 64 + l15 * 4;
      bf16x4 qv = *(const bf16x4*)&qs[qoff];
      const int ccol = c16 * 16 + l15;
#pragma unroll
      for (int r = 0; r < 4; ++r) {
        const int j = j16 * 16 + quad * 4 + r;
        out[((size_t)b * 2048 + j) * 512 + ccol] = (float)qv[r] * (w1[r] / w2[r]);
      }
    }
}

extern "C" void kernel_launch(void* const* d_in, const int* in_sizes, int n_in,
                              void* d_out, int out_size, void* d_ws, size_t ws_size,
                              hipStream_t stream) {
  const float* x = (const float*)d_in[0];
  const float* dis = (const float*)d_in[1];
  const float* Wq = (const float*)d_in[2];
  const float* Wk = (const float*)d_in[3];
  const float* Wv = (const float*)d_in[4];
  const float* alpha = (const float*)d_in[5];
  float* out = (float*)d_out;

  char* p = (char*)d_ws;
  bf16_t* x_bf = (bf16_t*)p;  p += (size_t)16384 * 512 * 2;       // 16 MB
  bf16_t* Wall = (bf16_t*)p;  p += (size_t)1536 * 512 * 2;        // 1.5 MB
  bf16_t* kwT  = (bf16_t*)p;  p += (size_t)8 * 512 * 2048 * 2;    // 16 MB
  bf16_t* kwvT = (bf16_t*)p;  p += (size_t)8 * 512 * 2048 * 2;    // 16 MB
  bf16_t* dwT  = (bf16_t*)p;  p += (size_t)8 * 2048 * 2048 * 2;   // 64 MB
  bf16_t* qs_bf = (bf16_t*)p; p += (size_t)16384 * 512 * 2;       // 16 MB (blocked layout)
  if ((size_t)(p - (char*)d_ws) > ws_size) return;  // ws too small: fail visibly

  // 128 KB dynamic LDS for main_gemm (>64 KB needs the opt-in attribute;
  // hipFuncSetAttribute is not a stream op -> graph-capture safe).
  static bool attr_done = false;
  if (!attr_done) {
    hipFuncSetAttribute(reinterpret_cast<const void*>(main_gemm),
                        hipFuncAttributeMaxDynamicSharedMemorySize, 131072);
    attr_done = true;
  }

  cvt_all<<<8960, 256, 0, stream>>>(x, Wq, Wk, Wv, x_bf, Wall);
  proj_dw<<<9728, 256, 0, stream>>>(x_bf, Wall, qs_bf, kwT, kwvT, dis, dwT, alpha);
  main_gemm<<<256, 512, 131072, stream>>>(dwT, kwvT, kwT, qs_bf, out);
}

// Round 8
// 307.843 us; speedup vs baseline: 1.1313x; 1.0189x over previous
//
#include <hip/hip_runtime.h>
#include <math.h>
#include <stdint.h>

// Problem constants: B=8, N=2048, D=512, H=16, dk=32
// q = x@Wq^T; k = x@Wk^T; v = x@Wv^T            [t=16384, c=512]
// dw[b,i,j] = exp(-alpha*11*dis[b,i,j])
// w1[b,j,c] = sum_i dw[b,i,j]*exp(k)[b,i,c]*v[b,i,c]
// w2[b,j,c] = sum_i dw[b,i,j]*exp(k)[b,i,c]
// out[b,j,c] = sigmoid(q)[b,j,c] * w1/w2

typedef __bf16 bf16_t;
typedef __attribute__((ext_vector_type(4))) __bf16 bf16x4;
typedef __attribute__((ext_vector_type(8))) __bf16 bf16x8;
typedef __attribute__((ext_vector_type(4))) float f32x4;

#define MFMA_BF16(a, b, c) __builtin_amdgcn_mfma_f32_16x16x32_bf16((a), (b), (c), 0, 0, 0)

static __device__ __forceinline__ void async_ld16(const bf16_t* g, bf16_t* lds) {
  __builtin_amdgcn_global_load_lds(
      reinterpret_cast<__attribute__((address_space(1))) unsigned int*>(
          reinterpret_cast<uintptr_t>(g)),
      reinterpret_cast<__attribute__((address_space(3))) unsigned int*>(
          reinterpret_cast<uintptr_t>(lds)),
      16, 0, 0);
}

// counted-vmcnt wait (T4). "memory" clobber orders surrounding mem ops; the
// sched_barrier stops hipcc hoisting register-only MFMA past it (rule #18).
#define WAITV(N)                                          \
  do {                                                    \
    asm volatile("s_waitcnt vmcnt(" #N ")" ::: "memory"); \
    __builtin_amdgcn_sched_barrier(0);                    \
  } while (0)

// ---- 3-bit XOR swizzle pair (hardware-validated) ----
// Stage ROWS x 64 bf16 tile: stored[row][pos] holds global chunk (pos ^ (row&7));
// swizzle applied via per-lane SOURCE address, LDS dest stays linear (rule #21).
template <int ROWS>
static __device__ __forceinline__ void stage3(const bf16_t* g, int ldg, bf16_t* lds,
                                              int wv, int lane) {
  const int r_in = lane >> 3;      // 8 chunks per 64-wide row
  const int cpos = lane & 7;
#pragma unroll
  for (int s = 0; s < ROWS / 32; ++s) {
    int rbase = wv * (ROWS / 4) + s * 8;   // multiple of 8 -> row&7 == r_in
    int row = rbase + r_in;
    int cg = cpos ^ (row & 7);
    async_ld16(g + (size_t)row * ldg + cg * 8, lds + rbase * 64 + lane * 8);
  }
}

// Swizzled fragment read (BK=64): logical chunk lc read at pos = lc ^ (row&7).
static __device__ __forceinline__ bf16x8 frag3(const bf16_t* lds, int row16,
                                               int l15, int quad, int kc) {
  int p = (quad | (kc << 2)) ^ (l15 & 7);
  return *(const bf16x8*)&lds[(row16 + l15) * 64 + p * 8];
}

// ---------------- fused fp32 -> bf16 conversion ----------------
__global__ __launch_bounds__(256) void cvt_all(const float* __restrict__ x,
                                               const float* __restrict__ wq,
                                               const float* __restrict__ wk,
                                               const float* __restrict__ wv,
                                               bf16_t* __restrict__ xb,
                                               bf16_t* __restrict__ wall) {
  int i = blockIdx.x * 256 + threadIdx.x;  // f32x4 index
  if (i >= 2293760) return;
  const float* src;
  bf16_t* dst;
  int off;
  if (i < 2097152) {
    src = x; dst = xb; off = i;
  } else {
    int j = i - 2097152;
    int sel = j >> 16;        // 65536 f32x4 per weight
    off = j & 65535;
    src = (sel == 0) ? wq : (sel == 1) ? wk : wv;
    dst = wall + (size_t)sel * 262144;
  }
  f32x4 f = ((const f32x4*)src)[off];
  bf16x4 o;
  o[0] = (bf16_t)f[0]; o[1] = (bf16_t)f[1]; o[2] = (bf16_t)f[2]; o[3] = (bf16_t)f[3];
  ((bf16x4*)dst)[off] = o;
}

// ---------------- merged projection GEMM + dis-weight transpose ----------------
// (unchanged from round 6 — verified; conflicts already collapsed to 393K)
__global__ __launch_bounds__(256, 4) void proj_dw(const bf16_t* __restrict__ A,
                                                  const bf16_t* __restrict__ W,
                                                  bf16_t* __restrict__ qs,
                                                  bf16_t* __restrict__ kwT,
                                                  bf16_t* __restrict__ kwvT,
                                                  const float* __restrict__ dis,
                                                  bf16_t* __restrict__ dwT,
                                                  const float* __restrict__ alpha) {
  __shared__ __align__(16) char pool[32768];
  const int tid = threadIdx.x;
  const int idx = blockIdx.x;
  const int g19 = idx / 19, r19 = idx % 19;

  if (r19 >= 3) {
    // ---------------- dw path ----------------
    int sub = g19 * 16 + (r19 - 3);
    int jt = sub & 31, it = (sub >> 5) & 31, b = sub >> 10;
    bf16_t* t = (bf16_t*)pool;  // 64*65*2 = 8320 B
    const float coef = -alpha[0] * 11.0f;  // log2(2048) == 11
    const int j0 = jt * 64, i0 = it * 64;
    const int rr = tid >> 4, cc = (tid & 15) * 4;
#pragma unroll
    for (int p = 0; p < 4; ++p) {
      int i = rr + p * 16;
      f32x4 d = *(const f32x4*)&dis[((size_t)(b * 2048 + i0 + i)) * 2048 + j0 + cc];
#pragma unroll
      for (int e = 0; e < 4; ++e) t[(cc + e) * 65 + i] = (bf16_t)__expf(coef * d[e]);
    }
    __syncthreads();
#pragma unroll
    for (int p = 0; p < 4; ++p) {
      int j = rr + p * 16;
      bf16x4 o;
#pragma unroll
      for (int e = 0; e < 4; ++e) o[e] = t[j * 65 + cc + e];
      *(bf16x4*)&dwT[((size_t)(b * 2048 + j0 + j)) * 2048 + i0 + cc] = o;
    }
    return;
  }

  // ---------------- proj path ----------------
  const int sub = g19 * 3 + r19;
  const int m_blk = sub / 12, n_blk = sub % 12;
  bf16_t* As = (bf16_t*)pool;  // 128x64 = 16 KB
  const int K = 512;
  const int wv = tid >> 6, lane = tid & 63;
  const int l15 = lane & 15, quad = lane >> 4;
  const int wm = wv >> 1, wn = wv & 1;
  const bf16_t* Am = A + (size_t)(m_blk * 128) * K;
  const int b = m_blk >> 4;

  if (n_blk < 4) {
    // ---- q path: 128x128 tile, 64x64 wave tiles, BK=64 ----
    bf16_t* Bsq = (bf16_t*)(pool + 16384);  // 128x64 = 16 KB
    const int c_loc = n_blk * 128;
    f32x4 acc[4][4];
#pragma unroll
    for (int a = 0; a < 4; ++a)
#pragma unroll
      for (int c = 0; c < 4; ++c) acc[a][c] = (f32x4){0.f, 0.f, 0.f, 0.f};

    for (int k0 = 0; k0 < K; k0 += 64) {
      stage3<128>(Am + k0, K, As, wv, lane);
      stage3<128>(W + (size_t)c_loc * K + k0, K, Bsq, wv, lane);
      __syncthreads();
#pragma unroll
      for (int kc = 0; kc < 2; ++kc) {
        bf16x8 a[4], bb[4];
#pragma unroll
        for (int mf = 0; mf < 4; ++mf) a[mf] = frag3(As, wm * 64 + mf * 16, l15, quad, kc);
#pragma unroll
        for (int nf = 0; nf < 4; ++nf) bb[nf] = frag3(Bsq, wn * 64 + nf * 16, l15, quad, kc);
#pragma unroll
        for (int mf = 0; mf < 4; ++mf)
#pragma unroll
          for (int nf = 0; nf < 4; ++nf) acc[mf][nf] = MFMA_BF16(a[mf], bb[nf], acc[mf][nf]);
      }
      __syncthreads();
    }
#pragma unroll
    for (int mf = 0; mf < 4; ++mf)
#pragma unroll
      for (int nf = 0; nf < 4; ++nf) {
        int j16 = (m_blk & 15) * 8 + wm * 4 + mf;
        int c16 = n_blk * 8 + wn * 4 + nf;
        bf16x4 o;
#pragma unroll
        for (int r = 0; r < 4; ++r)
          o[r] = (bf16_t)(1.0f / (1.0f + __expf(-acc[mf][nf][r])));
        size_t off = (((size_t)b * 128 + j16) * 32 + c16) * 256 + quad * 64 + l15 * 4;
        *(bf16x4*)&qs[off] = o;
      }
  } else {
    // ---- kv path: 128x64 tile, 64x32 wave tiles, k and v share A staging, BK=64 ----
    bf16_t* Bk = (bf16_t*)(pool + 16384);  // 64x64 = 8 KB
    bf16_t* Bv = (bf16_t*)(pool + 24576);  // 64x64 = 8 KB
    const int c_loc = (n_blk - 4) * 64;
    f32x4 acck[4][2], accv[4][2];
#pragma unroll
    for (int a = 0; a < 4; ++a)
#pragma unroll
      for (int c = 0; c < 2; ++c) {
        acck[a][c] = (f32x4){0.f, 0.f, 0.f, 0.f};
        accv[a][c] = (f32x4){0.f, 0.f, 0.f, 0.f};
      }
    const bf16_t* Wk = W + (size_t)(512 + c_loc) * K;
    const bf16_t* Wv = W + (size_t)(1024 + c_loc) * K;

    for (int k0 = 0; k0 < K; k0 += 64) {
      stage3<128>(Am + k0, K, As, wv, lane);
      stage3<64>(Wk + k0, K, Bk, wv, lane);
      stage3<64>(Wv + k0, K, Bv, wv, lane);
      __syncthreads();
#pragma unroll
      for (int kc = 0; kc < 2; ++kc) {
        bf16x8 a[4], bk[2], bv[2];
#pragma unroll
        for (int mf = 0; mf < 4; ++mf) a[mf] = frag3(As, wm * 64 + mf * 16, l15, quad, kc);
#pragma unroll
        for (int nf = 0; nf < 2; ++nf) {
          bk[nf] = frag3(Bk, wn * 32 + nf * 16, l15, quad, kc);
          bv[nf] = frag3(Bv, wn * 32 + nf * 16, l15, quad, kc);
        }
#pragma unroll
        for (int mf = 0; mf < 4; ++mf)
#pragma unroll
          for (int nf = 0; nf < 2; ++nf) {
            acck[mf][nf] = MFMA_BF16(a[mf], bk[nf], acck[mf][nf]);
            accv[mf][nf] = MFMA_BF16(a[mf], bv[nf], accv[mf][nf]);
          }
      }
      __syncthreads();
    }

    // epilogue: exp/mul + 32-c-chunk transpose through aliased LDS
    bf16_t* Lk = (bf16_t*)pool;            // 32 x 136 = 8704 B
    bf16_t* Lv = (bf16_t*)(pool + 8704);   // 32 x 136 = 8704 B
    const int t0 = (m_blk * 128) & 2047;
#pragma unroll
    for (int ci = 0; ci < 2; ++ci) {
      if (wn == ci) {
#pragma unroll
        for (int mf = 0; mf < 4; ++mf)
#pragma unroll
          for (int nf = 0; nf < 2; ++nf) {
            int cl = nf * 16 + l15;
            int tl = wm * 64 + mf * 16 + quad * 4;
#pragma unroll
            for (int r = 0; r < 4; ++r) {
              float kw = __expf(acck[mf][nf][r]);
              Lk[cl * 136 + tl + r] = (bf16_t)kw;
              Lv[cl * 136 + tl + r] = (bf16_t)(kw * accv[mf][nf][r]);
            }
          }
      }
      __syncthreads();
      {
        int rowt = tid >> 3, colt = (tid & 7) * 16;
        int c = c_loc + ci * 32 + rowt;
        size_t g = ((size_t)b * 512 + c) * 2048 + t0 + colt;
        *(bf16x8*)&kwT[g] = *(const bf16x8*)&Lk[rowt * 136 + colt];
        *(bf16x8*)&kwT[g + 8] = *(const bf16x8*)&Lk[rowt * 136 + colt + 8];
        *(bf16x8*)&kwvT[g] = *(const bf16x8*)&Lv[rowt * 136 + colt];
        *(bf16x8*)&kwvT[g + 8] = *(const bf16x8*)&Lv[rowt * 136 + colt + 8];
      }
      __syncthreads();
    }
  }
}

// ---------------- main batched GEMM + fused epilogue ----------------
// 256^2 / 8-wave (2M x 4N) / BK=64 / 4 phases / 2 x 64 KB LDS buffers.
// T4 counted vmcnt: tile t+1 staged in 8 chunks distributed across t's phases
// in t+1's READ order (ph0: A0,A2,B0',B1'; ph1: B2',B3'; ph2: A1,A3).
// Waits are counted, never vmcnt(0) mid-loop:
//   boundary WAITV(4)  -> publishes next tile's first 4 chunks (4 stay in flight)
//   ph0/ph1  WAITV(6)  -> publishes the 2 chunks the next phase reads
// Per-wave FIFO vmcnt semantics (m135) + identical per-wave wait sequences
// before each s_barrier give block-wide visibility. The LDS image per tile is
// byte-identical to the round-3/6-verified kernel; only issue order/waits changed.
// One full drain at t=30 handles the tail.
__global__ __launch_bounds__(512, 2) void main_gemm(const bf16_t* __restrict__ dwT,
                                                    const bf16_t* __restrict__ kwvT,
                                                    const bf16_t* __restrict__ kwT,
                                                    const bf16_t* __restrict__ qs,
                                                    float* __restrict__ out) {
  extern __shared__ __align__(16) char smem_raw[];
  bf16_t* const lds = (bf16_t*)smem_raw;  // [2 buf][A 16384 | B 16384] elements
  const int K = 2048;
  const int tid = threadIdx.x;
  const int wv = tid >> 6, lane = tid & 63;
  const int l15 = lane & 15, quad = lane >> 4;
  const int bi = blockIdx.x;
  const int b = bi & 7, nbb = (bi >> 3) & 3, mb = bi >> 5;
  const int wm = wv >> 2, wn = wv & 3;       // 2 m-waves x 4 n-waves
  const int r_in = lane >> 3, cpos = lane & 7;
  const int cg = cpos ^ r_in;                // 3-bit swizzled source chunk (row&7 == r_in)

  const bf16_t* const Ab = dwT + ((size_t)b * 2048 + mb * 256) * K;
  const bf16_t* const BvB = kwvT + (size_t)b * 512 * K;
  const bf16_t* const BkB = kwT + (size_t)b * 512 * K;

  // A chunks s=0..3: rows s*64 + wv*8 + r_in (read order: s0,s2 then s1,s3).
  const bf16_t* aSrc[4];
  int aDst[4];
#pragma unroll
  for (int s = 0; s < 4; ++s) {
    const int row = s * 64 + wv * 8 + r_in;
    aSrc[s] = Ab + (size_t)row * K + cg * 8;
    aDst[s] = s * 4096 + wv * 512 + lane * 8;
  }
  // B chunks cb=0..3 = read-order quarters of the interleaved B rows:
  //   cb0: rows {0-31, 64-95}   (wn=0,1 nh=0)   cb1: {128-159, 192-223} (wn=2,3 nh=0)
  //   cb2: rows {32-63, 96-127} (wn=0,1 nh=1)   cb3: {160-191, 224-255} (wn=2,3 nh=1)
  // Wave wv: half h=wv>>2 (+64 rows), sub w4=wv&3 (8 rows) -> per-wave-linear burst.
  const bf16_t* bSrc[4];
  int bDst[4];
#pragma unroll
  for (int cb = 0; cb < 4; ++cb) {
    const int base1 = (cb & 1) * 128 + (cb >> 1) * 32;
    const int rowbase = base1 + (wv >> 2) * 64 + (wv & 3) * 8;
    const int row = rowbase + r_in;            // row&7 == r_in (bases mult. of 8)
    const int type = (row >> 4) & 1;           // 0 -> kwv (w1), 1 -> kw (w2)
    const int crow = nbb * 128 + (row >> 5) * 16 + (row & 15);
    bSrc[cb] = (type ? BkB : BvB) + (size_t)crow * K + cg * 8;
    bDst[cb] = 16384 + rowbase * 64 + lane * 8;
  }

  f32x4 acc[8][4];
#pragma unroll
  for (int m = 0; m < 8; ++m)
#pragma unroll
    for (int n = 0; n < 4; ++n) acc[m][n] = (f32x4){0.f, 0.f, 0.f, 0.f};

  bf16x8 a[8];   // current A m-half: [mf*2+kc]
  bf16x8 b0[4];  // B n-half 0: [nf*2+kc]
  bf16x8 b1[4];  // B n-half 1

#define STAGE_A(dst, s, koff) async_ld16(aSrc[s] + (koff), lds + (dst)*32768 + aDst[s])
#define STAGE_B(dst, cb, koff) async_ld16(bSrc[cb] + (koff), lds + (dst)*32768 + bDst[cb])

#define LOADA(As_, mh)                                                             \
  do {                                                                             \
    _Pragma("unroll") for (int mf = 0; mf < 4; ++mf)                               \
        _Pragma("unroll") for (int kc = 0; kc < 2; ++kc)                           \
            a[mf * 2 + kc] =                                                       \
        frag3((As_), wm * 128 + (mh)*64 + mf * 16, l15, quad, kc);                 \
  } while (0)

#define LOADB(Bs_, dstarr, nh)                                                     \
  do {                                                                             \
    _Pragma("unroll") for (int nf = 0; nf < 2; ++nf)                               \
        _Pragma("unroll") for (int kc = 0; kc < 2; ++kc)                           \
            dstarr[nf * 2 + kc] =                                                  \
        frag3((Bs_), wn * 64 + (nh)*32 + nf * 16, l15, quad, kc);                  \
  } while (0)

#define MFMA_PH(mh, nh, barr)                                                      \
  do {                                                                             \
    __builtin_amdgcn_s_setprio(1);                                                 \
    _Pragma("unroll") for (int kc = 0; kc < 2; ++kc)                               \
        _Pragma("unroll") for (int mf = 0; mf < 4; ++mf)                           \
            _Pragma("unroll") for (int nf = 0; nf < 2; ++nf)                       \
                acc[(mh)*4 + mf][(nh)*2 + nf] =                                    \
        MFMA_BF16(a[mf * 2 + kc], barr[nf * 2 + kc], acc[(mh)*4 + mf][(nh)*2 + nf]); \
    __builtin_amdgcn_s_setprio(0);                                                 \
  } while (0)

  // prologue: tile 0's 8 chunks in read order; publish first 4, keep 4 in flight.
  STAGE_A(0, 0, 0); STAGE_A(0, 2, 0); STAGE_B(0, 0, 0); STAGE_B(0, 1, 0);
  STAGE_B(0, 2, 0); STAGE_B(0, 3, 0); STAGE_A(0, 1, 0); STAGE_A(0, 3, 0);
  WAITV(4);
  __builtin_amdgcn_s_barrier();

  for (int t = 0; t < 32; ++t) {
    const int c = t & 1;
    const int nx = c ^ 1;
    const bf16_t* As_c = lds + c * 32768;
    const bf16_t* Bs_c = As_c + 16384;
    const int ko = (t + 1) * 64;
    // phase 0: issue t+1's first-read chunks; compute (m0,n0)
    if (t < 31) { STAGE_A(nx, 0, ko); STAGE_A(nx, 2, ko); STAGE_B(nx, 0, ko); STAGE_B(nx, 1, ko); }
    LOADA(As_c, 0);
    LOADB(Bs_c, b0, 0);
    __builtin_amdgcn_s_barrier();
    MFMA_PH(0, 0, b0);
    WAITV(6);                       // publish this tile's B2',B3'
    __builtin_amdgcn_s_barrier();
    // phase 1: issue t+1's B2',B3'; compute (m0,n1)
    if (t < 31) { STAGE_B(nx, 2, ko); STAGE_B(nx, 3, ko); }
    LOADB(Bs_c, b1, 1);
    __builtin_amdgcn_s_barrier();
    MFMA_PH(0, 1, b1);
    WAITV(6);                       // publish this tile's A1,A3
    __builtin_amdgcn_s_barrier();
    // phase 2: issue t+1's A1,A3; compute (m1,n1)
    if (t < 31) { STAGE_A(nx, 1, ko); STAGE_A(nx, 3, ko); }
    LOADA(As_c, 1);
    __builtin_amdgcn_s_barrier();
    MFMA_PH(1, 1, b1);
    __builtin_amdgcn_s_barrier();
    // phase 3: compute (m1,n0) from registers; counted boundary publish
    MFMA_PH(1, 0, b0);
    if (t < 30) {
      WAITV(4);                     // publish t+1's first 4 chunks; 4 stay in flight
      __builtin_amdgcn_s_barrier();
    } else if (t == 30) {
      WAITV(0);                     // tail drain: all of tile 31 resident
      __builtin_amdgcn_s_barrier();
    }
  }

#undef STAGE_A
#undef STAGE_B
#undef LOADA
#undef LOADB
#undef MFMA_PH

  // epilogue: nf even = w1 (kwv), nf odd = w2 (kw); pair in registers.
#pragma unroll
  for (int mf = 0; mf < 8; ++mf)
#pragma unroll
    for (int p = 0; p < 2; ++p) {
      f32x4 w1 = acc[mf][2 * p];
      f32x4 w2 = acc[mf][2 * p + 1];
      const int j16 = mb * 16 + wm * 8 + mf;
      const int c16 = nbb * 8 + wn * 2 + p;
      size_t qoff = (((size_t)b * 128 + j16) * 32 + c16) * 256 + quad * 64 + l15 * 4;
      bf16x4 qv = *(const bf16x4*)&qs[qoff];
      const int ccol = c16 * 16 + l15;
#pragma unroll
      for (int r = 0; r < 4; ++r) {
        const int j = j16 * 16 + quad * 4 + r;
        out[((size_t)b * 2048 + j) * 512 + ccol] = (float)qv[r] * (w1[r] / w2[r]);
      }
    }
}

extern "C" void kernel_launch(void* const* d_in, const int* in_sizes, int n_in,
                              void* d_out, int out_size, void* d_ws, size_t ws_size,
                              hipStream_t stream) {
  const float* x = (const float*)d_in[0];
  const float* dis = (const float*)d_in[1];
  const float* Wq = (const float*)d_in[2];
  const float* Wk = (const float*)d_in[3];
  const float* Wv = (const float*)d_in[4];
  const float* alpha = (const float*)d_in[5];
  float* out = (float*)d_out;

  char* p = (char*)d_ws;
  bf16_t* x_bf = (bf16_t*)p;  p += (size_t)16384 * 512 * 2;       // 16 MB
  bf16_t* Wall = (bf16_t*)p;  p += (size_t)1536 * 512 * 2;        // 1.5 MB
  bf16_t* kwT  = (bf16_t*)p;  p += (size_t)8 * 512 * 2048 * 2;    // 16 MB
  bf16_t* kwvT = (bf16_t*)p;  p += (size_t)8 * 512 * 2048 * 2;    // 16 MB
  bf16_t* dwT  = (bf16_t*)p;  p += (size_t)8 * 2048 * 2048 * 2;   // 64 MB
  bf16_t* qs_bf = (bf16_t*)p; p += (size_t)16384 * 512 * 2;       // 16 MB (blocked layout)
  if ((size_t)(p - (char*)d_ws) > ws_size) return;  // ws too small: fail visibly

  // 128 KB dynamic LDS for main_gemm (>64 KB needs the opt-in attribute;
  // hipFuncSetAttribute is not a stream op -> graph-capture safe).
  static bool attr_done = false;
  if (!attr_done) {
    hipFuncSetAttribute(reinterpret_cast<const void*>(main_gemm),
                        hipFuncAttributeMaxDynamicSharedMemorySize, 131072);
    attr_done = true;
  }

  cvt_all<<<8960, 256, 0, stream>>>(x, Wq, Wk, Wv, x_bf, Wall);
  proj_dw<<<9728, 256, 0, stream>>>(x_bf, Wall, qs_bf, kwT, kwvT, dis, dwT, alpha);
  main_gemm<<<256, 512, 131072, stream>>>(dwT, kwvT, kwT, qs_bf, out);
}